// Round 19
// baseline (253.850 us; speedup 1.0000x reference)
//
#include <hip/hip_runtime.h>

#define SCALE 0.17677669529663687f
#define LOG2E 1.4426950408889634f

typedef __attribute__((ext_vector_type(8))) short short8;
typedef __attribute__((ext_vector_type(4))) float f32x4;
typedef __attribute__((ext_vector_type(4))) _Float16 half4;

__device__ __forceinline__ f32x4 MFMA32(short8 a, short8 b, f32x4 c) {
  return __builtin_amdgcn_mfma_f32_16x16x32_bf16(a, b, c, 0, 0, 0);
}

__device__ __forceinline__ f32x4 MFMA16(half4 a, half4 b, f32x4 c) {
  return __builtin_amdgcn_mfma_f32_16x16x16f16(a, b, c, 0, 0, 0);
}

__device__ __forceinline__ unsigned short f2bf(float f) {
  unsigned u = __float_as_uint(f);
  u += 0x7fffu + ((u >> 16) & 1u);
  return (unsigned short)(u >> 16);
}

// HW packed f32->bf16 (2 elems / instr) — replaces ~17-VALU bit-twiddle pack4.
__device__ __forceinline__ unsigned long long pack4(float a, float b, float c, float d) {
  unsigned lo, hi;
  asm("v_cvt_pk_bf16_f32 %0, %1, %2" : "=v"(lo) : "v"(a), "v"(b));
  asm("v_cvt_pk_bf16_f32 %0, %1, %2" : "=v"(hi) : "v"(c), "v"(d));
  return (unsigned long long)lo | ((unsigned long long)hi << 32);
}

// ---- Prologue: PRE-SWIZZLED (per-lane fragment order) weight/rpe buffers.
//   qkv_wb: [(o*8+h)*2+m][ks][lane][8] bf16  (o=0 q-rows pre-scaled by
//           SCALE*LOG2E for exp2-domain softmax)
//   proj_wb:[h*2+m][ks][lane][8] bf16
//   rpe:    [(h*4+it)*4+jt][lane][4] f32, pre-scaled by LOG2E
// 1155*256 = 295680 threads exact.
__global__ void prep_kernel(const float* __restrict__ qkv_w,
                            const float* __restrict__ proj_w,
                            const float* __restrict__ table,
                            const int* __restrict__ rel,
                            const float* __restrict__ qkv_b,
                            unsigned short* __restrict__ qkv_wb,
                            unsigned short* __restrict__ proj_wb,
                            float* __restrict__ rpe,
                            float* __restrict__ qkv_bs) {
  int idx = blockIdx.x * 256 + threadIdx.x;
  if (idx < 196608) {
    int e    = idx & 7;
    int lane = (idx >> 3) & 63;
    int ks   = (idx >> 9) & 7;
    int m    = (idx >> 12) & 1;
    int h    = (idx >> 13) & 7;
    int o    = idx >> 16;                    // 0=q 1=k 2=v
    int lr = lane & 15, lg = lane >> 4;
    int row = o * 256 + h * 32 + m * 16 + lr;
    int col = ks * 32 + lg * 8 + e;
    float v = qkv_w[row * 256 + col];
    if (o == 0) v *= SCALE * LOG2E;
    qkv_wb[idx] = f2bf(v);
  } else if (idx < 262144) {
    int p = idx - 196608;
    int e    = p & 7;
    int lane = (p >> 3) & 63;
    int ks   = (p >> 9) & 7;
    int m    = (p >> 12) & 1;
    int h    = (p >> 13) & 7;
    int lr = lane & 15, lg = lane >> 4;
    int row = h * 32 + m * 16 + lr;
    int col = ks * 32 + lg * 8 + e;
    proj_wb[p] = f2bf(proj_w[row * 256 + col]);
  } else if (idx < 294912) {
    int t = idx - 262144;                    // packed rpe (exp2-domain)
    int e    = t & 3;
    int lane = (t >> 2) & 63;
    int jt   = (t >> 8) & 3;
    int it   = (t >> 10) & 3;
    int h    = t >> 12;
    int lr = lane & 15, lg = lane >> 4;
    int i = it * 16 + lr;
    int j = jt * 16 + lg * 4 + e;
    rpe[t] = table[rel[i * 64 + j] * 8 + h] * LOG2E;
  } else {
    int i = idx - 294912;                    // 0..767
    qkv_bs[i] = qkv_b[i] * (i < 256 ? SCALE * LOG2E : 1.0f);
  }
}

// ---- Main fused kernel: 1024 blocks, each runs windows {bid + wi*1024},
// wi=0..3 — all share mask row bid. 8 waves = 8 heads.
// R19 = R18 + (a) 4 windows/block via xb0/xb1 double-buffer (pack for wi+1
// into the buffer whose phase-5 readers are fenced by B1(wi) — no new
// barriers; exposed x-latency now 1-in-4 windows, mask staged once per 4);
// (b) pack4 via v_cvt_pk_bf16_f32 (2 instr vs ~17 VALU).
// Natural regs at (512,2); caps spill (R3/R10/R11/R14/R15).
// Spill tripwire: WRITE >> 330 MB. cvt_pk operand-order tripwire: absmax.
__global__ __launch_bounds__(512, 2)
void win_attn_kernel(const float* __restrict__ x,
                     const float* __restrict__ mask,
                     const unsigned short* __restrict__ qkv_wb,
                     const float* __restrict__ qkv_bs,
                     const unsigned short* __restrict__ proj_wb,
                     const float* __restrict__ proj_b,
                     const float* __restrict__ rpe,
                     float* __restrict__ out) {
  __shared__ __align__(16) unsigned char smem[84992];
  unsigned short* xb0 = (unsigned short*)smem;            // [64][264] bf16
  unsigned short* xb1 = (unsigned short*)(smem + 33792);  // [64][264] bf16
  float*          mk  = (float*)(smem + 67584);           // [64][68] f32 (xLOG2E)
  const int bid  = blockIdx.x;
  const int tid  = threadIdx.x;
  const int w    = tid >> 6;     // wave = head
  const int lane = tid & 63;
  const int lr   = lane & 15;
  const int lg   = lane >> 4;

  // ---- Phase 1: stage x0 -> xb0 bf16 (nt); mask*LOG2E -> mk
  {
    const f32x4* xg = (const f32x4*)(x + (size_t)bid * 16384);
    const f32x4* mg = (const f32x4*)(mask + (size_t)bid * 4096);
    f32x4 rx[8], rm[2];
#pragma unroll
    for (int i = 0; i < 8; ++i)
      rx[i] = __builtin_nontemporal_load(&xg[i * 512 + tid]);
#pragma unroll
    for (int i = 0; i < 2; ++i)
      rm[i] = mg[i * 512 + tid];
#pragma unroll
    for (int i = 0; i < 8; ++i) {
      int vi = i * 512 + tid;
      *(unsigned long long*)&xb0[(vi >> 6) * 264 + (vi & 63) * 4]
          = pack4(rx[i][0], rx[i][1], rx[i][2], rx[i][3]);
    }
#pragma unroll
    for (int i = 0; i < 2; ++i) {
      int vi = i * 512 + tid;
      f32x4 sm;
#pragma unroll
      for (int e = 0; e < 4; ++e) sm[e] = rm[i][e] * LOG2E;
      *(f32x4*)&mk[(vi >> 4) * 68 + (vi & 15) * 4] = sm;
    }
  }
  __syncthreads();   // B0

#pragma unroll
  for (int wi = 0; wi < 4; ++wi) {
    unsigned short* xb  = (wi & 1) ? xb1 : xb0;
    unsigned short* xbn = (wi & 1) ? xb0 : xb1;   // next window's buffer

    // ---- Phase 2 (merged): qT, kT, v in ONE xf pass — 24 MFMA per ks.
    half4 qh[2][4], kh[2][4];    // [d-tile][tok-tile]
    half4 vh[4][2];              // [tok-tile = PV k-step][d-tile]
    {
      f32x4 qacc[2][4], kacc[2][4], vacc[4][2];
#pragma unroll
      for (int m = 0; m < 2; ++m) {
        f32x4 bq = *(const f32x4*)&qkv_bs[w * 32 + m * 16 + lg * 4];
        f32x4 bk = *(const f32x4*)&qkv_bs[256 + w * 32 + m * 16 + lg * 4];
#pragma unroll
        for (int t = 0; t < 4; ++t) {
          qacc[m][t] = bq;
          kacc[m][t] = bk;
        }
      }
#pragma unroll
      for (int n = 0; n < 2; ++n) {
        float bv = qkv_bs[512 + w * 32 + n * 16 + lr];
        f32x4 iv = {bv, bv, bv, bv};
#pragma unroll
        for (int t = 0; t < 4; ++t)
          vacc[t][n] = iv;
      }
      const unsigned short* wqp = qkv_wb + (size_t)((0 * 8 + w) * 2) * 4096 + lane * 8;
      const unsigned short* wkp = qkv_wb + (size_t)((1 * 8 + w) * 2) * 4096 + lane * 8;
      const unsigned short* wvp = qkv_wb + (size_t)((2 * 8 + w) * 2) * 4096 + lane * 8;
#pragma unroll
      for (int ks = 0; ks < 8; ++ks) {
        short8 xf[4];
#pragma unroll
        for (int t = 0; t < 4; ++t)
          xf[t] = *(const short8*)&xb[(t * 16 + lr) * 264 + ks * 32 + lg * 8];
        short8 wq[2], wk[2], wv[2];
#pragma unroll
        for (int m = 0; m < 2; ++m) {
          wq[m] = *(const short8*)&wqp[(m * 8 + ks) * 512];
          wk[m] = *(const short8*)&wkp[(m * 8 + ks) * 512];
          wv[m] = *(const short8*)&wvp[(m * 8 + ks) * 512];
        }
#pragma unroll
        for (int m = 0; m < 2; ++m)
#pragma unroll
          for (int t = 0; t < 4; ++t) {
            qacc[m][t] = MFMA32(wq[m], xf[t], qacc[m][t]);
            kacc[m][t] = MFMA32(wk[m], xf[t], kacc[m][t]);
            vacc[t][m] = MFMA32(xf[t], wv[m], vacc[t][m]);
          }
      }
#pragma unroll
      for (int m = 0; m < 2; ++m)
#pragma unroll
        for (int t = 0; t < 4; ++t)
#pragma unroll
          for (int e = 0; e < 4; ++e) {
            qh[m][t][e] = (_Float16)qacc[m][t][e];
            kh[m][t][e] = (_Float16)kacc[m][t][e];
            vh[t][m][e] = (_Float16)vacc[t][m][e];
          }
    }
    __syncthreads();   // B1: all waves done reading xb; phase-5(wi-1)
                       // readers of xbn are also past this point

    // issue next window's x loads (latency hides under softmax+PV);
    // sched_barrier pins the issue point (R12: compiler sinks otherwise).
    f32x4 rx1[8];
    if (wi < 3) {
      const f32x4* xg1 = (const f32x4*)(x + ((size_t)bid + (wi + 1) * 1024) * 16384);
#pragma unroll
      for (int i = 0; i < 8; ++i)
        rx1[i] = __builtin_nontemporal_load(&xg1[i * 512 + tid]);
      __builtin_amdgcn_sched_barrier(0);
    }

    // ---- Phase 3: S^T = k @ q^T (exp2-domain), C-init = rpe+mask;
    // pb = exp2(S) unnormalized; inv[it] applied after PV.
    half4 pb[4][4];    // [jt = PV k-step][it]
    float inv[4];
    {
      const float* rpe_h = rpe + (size_t)w * 4096 + lane * 4;   // packed
#pragma unroll
      for (int it = 0; it < 4; ++it) {
        f32x4 binit[4];
#pragma unroll
        for (int jt = 0; jt < 4; ++jt)
          binit[jt] = *(const f32x4*)&rpe_h[(it * 4 + jt) * 256];
#pragma unroll
        for (int jt = 0; jt < 4; ++jt) {
          f32x4 mv = *(const f32x4*)&mk[(it * 16 + lr) * 68 + jt * 16 + lg * 4];
#pragma unroll
          for (int e = 0; e < 4; ++e) binit[jt][e] += mv[e];
        }
        f32x4 sacc[4];
#pragma unroll
        for (int jt = 0; jt < 4; ++jt) {
          sacc[jt] = MFMA16(kh[0][jt], qh[0][it], binit[jt]);
          sacc[jt] = MFMA16(kh[1][jt], qh[1][it], sacc[jt]);
        }
        float sum = 0.f;
#pragma unroll
        for (int jt = 0; jt < 4; ++jt)
#pragma unroll
          for (int e = 0; e < 4; ++e) {
            sacc[jt][e] = exp2f(sacc[jt][e]);
            sum += sacc[jt][e];
          }
#pragma unroll
        for (int jt = 0; jt < 4; ++jt)
#pragma unroll
          for (int e = 0; e < 4; ++e)
            pb[jt][it][e] = (_Float16)sacc[jt][e];
        sum += __shfl_xor(sum, 16, 64);
        sum += __shfl_xor(sum, 32, 64);
        inv[it] = 1.0f / sum;
      }
    }

    // ---- Phase 4: O^T = V^T @ P^T (unnormalized); scale by inv[it]; -> xb
    {
      f32x4 oacc[2][4];   // [dt][it]
      const f32x4 z4 = {0.f, 0.f, 0.f, 0.f};
#pragma unroll
      for (int dt = 0; dt < 2; ++dt)
#pragma unroll
        for (int it = 0; it < 4; ++it)
          oacc[dt][it] = z4;
#pragma unroll
      for (int kj = 0; kj < 4; ++kj)
#pragma unroll
        for (int dt = 0; dt < 2; ++dt)
#pragma unroll
          for (int it = 0; it < 4; ++it)
            oacc[dt][it] = MFMA16(vh[kj][dt], pb[kj][it], oacc[dt][it]);
#pragma unroll
      for (int dt = 0; dt < 2; ++dt)
#pragma unroll
        for (int it = 0; it < 4; ++it)
          *(unsigned long long*)&xb[(it * 16 + lr) * 264 + w * 32 + dt * 16 + lg * 4]
              = pack4(oacc[dt][it][0] * inv[it], oacc[dt][it][1] * inv[it],
                      oacc[dt][it][2] * inv[it], oacc[dt][it][3] * inv[it]);
    }

    // pack next window's x (loads long complete) into xbn; B2 publishes it
    if (wi < 3) {
#pragma unroll
      for (int i = 0; i < 8; ++i) {
        int vi = i * 512 + tid;
        *(unsigned long long*)&xbn[(vi >> 6) * 264 + (vi & 63) * 4]
            = pack4(rx1[i][0], rx1[i][1], rx1[i][2], rx1[i][3]);
      }
    }
    __syncthreads();   // B2: O_all (and next x) visible

    // ---- Phase 5: out^T = proj_w @ O_all^T; bias in acc-init; nt stores
    {
      f32x4 pacc[2][4];
#pragma unroll
      for (int m = 0; m < 2; ++m) {
        f32x4 bp = *(const f32x4*)&proj_b[w * 32 + m * 16 + lg * 4];
#pragma unroll
        for (int t = 0; t < 4; ++t)
          pacc[m][t] = bp;
      }
      const unsigned short* pwp = proj_wb + (size_t)(w * 2) * 4096 + lane * 8;
#pragma unroll
      for (int ks = 0; ks < 8; ++ks) {
        short8 of[4];
#pragma unroll
        for (int t = 0; t < 4; ++t)
          of[t] = *(const short8*)&xb[(t * 16 + lr) * 264 + ks * 32 + lg * 8];
        short8 pw[2];
#pragma unroll
        for (int m = 0; m < 2; ++m)
          pw[m] = *(const short8*)&pwp[(m * 8 + ks) * 512];
#pragma unroll
        for (int m = 0; m < 2; ++m)
#pragma unroll
          for (int t = 0; t < 4; ++t)
            pacc[m][t] = MFMA32(pw[m], of[t], pacc[m][t]);
      }
      float* og = out + ((size_t)bid + (size_t)wi * 1024) * 16384;
#pragma unroll
      for (int m = 0; m < 2; ++m)
#pragma unroll
        for (int t = 0; t < 4; ++t)
          __builtin_nontemporal_store(pacc[m][t],
              (f32x4*)&og[(t * 16 + lr) * 256 + w * 32 + m * 16 + lg * 4]);
    }
  }
}

extern "C" void kernel_launch(void* const* d_in, const int* in_sizes, int n_in,
                              void* d_out, int out_size, void* d_ws, size_t ws_size,
                              hipStream_t stream) {
  (void)in_sizes; (void)n_in; (void)out_size; (void)ws_size;
  const float* x      = (const float*)d_in[0];
  const float* mask   = (const float*)d_in[1];
  const float* qkv_w  = (const float*)d_in[2];
  const float* qkv_b  = (const float*)d_in[3];
  const float* proj_w = (const float*)d_in[4];
  const float* proj_b = (const float*)d_in[5];
  const float* rpb    = (const float*)d_in[6];
  const int*   rel    = (const int*)d_in[7];

  unsigned short* qkv_wb  = (unsigned short*)d_ws;                       // 393216 B
  unsigned short* proj_wb = (unsigned short*)((char*)d_ws + 393216);     // 131072 B
  float*          rpe     = (float*)((char*)d_ws + 524288);              // 131072 B
  float*          qkv_bs  = (float*)((char*)d_ws + 655360);              // 3072 B
  float*          out     = (float*)d_out;

  prep_kernel<<<dim3(1155), dim3(256), 0, stream>>>(qkv_w, proj_w, rpb, rel, qkv_b,
                                                    qkv_wb, proj_wb, rpe, qkv_bs);
  win_attn_kernel<<<dim3(1024), dim3(512), 0, stream>>>(x, mask, qkv_wb, qkv_bs,
                                                        proj_wb, proj_b, rpe, out);
}

// Round 20
// 239.099 us; speedup vs baseline: 1.0617x; 1.0617x over previous
//
#include <hip/hip_runtime.h>

#define SCALE 0.17677669529663687f
#define LOG2E 1.4426950408889634f

typedef __attribute__((ext_vector_type(8))) short short8;
typedef __attribute__((ext_vector_type(4))) float f32x4;
typedef __attribute__((ext_vector_type(4))) _Float16 half4;

__device__ __forceinline__ f32x4 MFMA32(short8 a, short8 b, f32x4 c) {
  return __builtin_amdgcn_mfma_f32_16x16x32_bf16(a, b, c, 0, 0, 0);
}

__device__ __forceinline__ f32x4 MFMA16(half4 a, half4 b, f32x4 c) {
  return __builtin_amdgcn_mfma_f32_16x16x16f16(a, b, c, 0, 0, 0);
}

__device__ __forceinline__ unsigned short f2bf(float f) {
  unsigned u = __float_as_uint(f);
  u += 0x7fffu + ((u >> 16) & 1u);
  return (unsigned short)(u >> 16);
}

// HW packed f32->bf16 (2 elems / instr) — replaces ~17-VALU bit-twiddle pack4.
// Validated in R19 (absmax unchanged at 9.77e-4).
__device__ __forceinline__ unsigned long long pack4(float a, float b, float c, float d) {
  unsigned lo, hi;
  asm("v_cvt_pk_bf16_f32 %0, %1, %2" : "=v"(lo) : "v"(a), "v"(b));
  asm("v_cvt_pk_bf16_f32 %0, %1, %2" : "=v"(hi) : "v"(c), "v"(d));
  return (unsigned long long)lo | ((unsigned long long)hi << 32);
}

// ---- Prologue: PRE-SWIZZLED (per-lane fragment order) weight/rpe buffers.
//   qkv_wb: [(o*8+h)*2+m][ks][lane][8] bf16  (o=0 q-rows pre-scaled by
//           SCALE*LOG2E for exp2-domain softmax)
//   proj_wb:[h*2+m][ks][lane][8] bf16
//   rpe:    [(h*4+it)*4+jt][lane][4] f32, pre-scaled by LOG2E
// 1155*256 = 295680 threads exact.
__global__ void prep_kernel(const float* __restrict__ qkv_w,
                            const float* __restrict__ proj_w,
                            const float* __restrict__ table,
                            const int* __restrict__ rel,
                            const float* __restrict__ qkv_b,
                            unsigned short* __restrict__ qkv_wb,
                            unsigned short* __restrict__ proj_wb,
                            float* __restrict__ rpe,
                            float* __restrict__ qkv_bs) {
  int idx = blockIdx.x * 256 + threadIdx.x;
  if (idx < 196608) {
    int e    = idx & 7;
    int lane = (idx >> 3) & 63;
    int ks   = (idx >> 9) & 7;
    int m    = (idx >> 12) & 1;
    int h    = (idx >> 13) & 7;
    int o    = idx >> 16;                    // 0=q 1=k 2=v
    int lr = lane & 15, lg = lane >> 4;
    int row = o * 256 + h * 32 + m * 16 + lr;
    int col = ks * 32 + lg * 8 + e;
    float v = qkv_w[row * 256 + col];
    if (o == 0) v *= SCALE * LOG2E;
    qkv_wb[idx] = f2bf(v);
  } else if (idx < 262144) {
    int p = idx - 196608;
    int e    = p & 7;
    int lane = (p >> 3) & 63;
    int ks   = (p >> 9) & 7;
    int m    = (p >> 12) & 1;
    int h    = (p >> 13) & 7;
    int lr = lane & 15, lg = lane >> 4;
    int row = h * 32 + m * 16 + lr;
    int col = ks * 32 + lg * 8 + e;
    proj_wb[p] = f2bf(proj_w[row * 256 + col]);
  } else if (idx < 294912) {
    int t = idx - 262144;                    // packed rpe (exp2-domain)
    int e    = t & 3;
    int lane = (t >> 2) & 63;
    int jt   = (t >> 8) & 3;
    int it   = (t >> 10) & 3;
    int h    = t >> 12;
    int lr = lane & 15, lg = lane >> 4;
    int i = it * 16 + lr;
    int j = jt * 16 + lg * 4 + e;
    rpe[t] = table[rel[i * 64 + j] * 8 + h] * LOG2E;
  } else {
    int i = idx - 294912;                    // 0..767
    qkv_bs[i] = qkv_b[i] * (i < 256 ? SCALE * LOG2E : 1.0f);
  }
}

// ---- Main fused kernel: 2048 blocks, each runs windows {bid, bid+2048}
// (identical shift mask). 8 waves = 8 heads.
// R20 = R18 (best structure: 2 windows/block, 8 block-rounds/CU slack)
//     + R19's proven cvt_pk pack4 (VALUBusy 28->25). R19's 4-window
//     variant REVERTED: grid 1024 = 4 zero-slack rounds/CU, tail imbalance
//     cost more than the saved 1-in-4 x-latency.
// Natural regs at (512,2); caps spill (R3/R10/R11/R14/R15).
__global__ __launch_bounds__(512, 2)
void win_attn_kernel(const float* __restrict__ x,
                     const float* __restrict__ mask,
                     const unsigned short* __restrict__ qkv_wb,
                     const float* __restrict__ qkv_bs,
                     const unsigned short* __restrict__ proj_wb,
                     const float* __restrict__ proj_b,
                     const float* __restrict__ rpe,
                     float* __restrict__ out) {
  __shared__ __align__(16) unsigned char smem[84992];
  unsigned short* xb0 = (unsigned short*)smem;            // [64][264] bf16
  unsigned short* xb1 = (unsigned short*)(smem + 33792);  // [64][264] bf16
  float*          mk  = (float*)(smem + 67584);           // [64][68] f32 (xLOG2E)
  const int bid  = blockIdx.x;
  const int tid  = threadIdx.x;
  const int w    = tid >> 6;     // wave = head
  const int lane = tid & 63;
  const int lr   = lane & 15;
  const int lg   = lane >> 4;

  // ---- Phase 1: stage x0 -> xb0 bf16 (nt); mask*LOG2E -> mk
  {
    const f32x4* xg = (const f32x4*)(x + (size_t)bid * 16384);
    const f32x4* mg = (const f32x4*)(mask + (size_t)(bid & 1023) * 4096);
    f32x4 rx[8], rm[2];
#pragma unroll
    for (int i = 0; i < 8; ++i)
      rx[i] = __builtin_nontemporal_load(&xg[i * 512 + tid]);
#pragma unroll
    for (int i = 0; i < 2; ++i)
      rm[i] = mg[i * 512 + tid];
#pragma unroll
    for (int i = 0; i < 8; ++i) {
      int vi = i * 512 + tid;
      *(unsigned long long*)&xb0[(vi >> 6) * 264 + (vi & 63) * 4]
          = pack4(rx[i][0], rx[i][1], rx[i][2], rx[i][3]);
    }
#pragma unroll
    for (int i = 0; i < 2; ++i) {
      int vi = i * 512 + tid;
      f32x4 sm;
#pragma unroll
      for (int e = 0; e < 4; ++e) sm[e] = rm[i][e] * LOG2E;
      *(f32x4*)&mk[(vi >> 4) * 68 + (vi & 15) * 4] = sm;
    }
  }
  __syncthreads();   // B0

#pragma unroll
  for (int wi = 0; wi < 2; ++wi) {
    unsigned short* xb = wi ? xb1 : xb0;

    // ---- Phase 2 (merged): qT, kT, v in ONE xf pass — 24 MFMA per ks.
    half4 qh[2][4], kh[2][4];    // [d-tile][tok-tile]
    half4 vh[4][2];              // [tok-tile = PV k-step][d-tile]
    {
      f32x4 qacc[2][4], kacc[2][4], vacc[4][2];
#pragma unroll
      for (int m = 0; m < 2; ++m) {
        f32x4 bq = *(const f32x4*)&qkv_bs[w * 32 + m * 16 + lg * 4];
        f32x4 bk = *(const f32x4*)&qkv_bs[256 + w * 32 + m * 16 + lg * 4];
#pragma unroll
        for (int t = 0; t < 4; ++t) {
          qacc[m][t] = bq;
          kacc[m][t] = bk;
        }
      }
#pragma unroll
      for (int n = 0; n < 2; ++n) {
        float bv = qkv_bs[512 + w * 32 + n * 16 + lr];
        f32x4 iv = {bv, bv, bv, bv};
#pragma unroll
        for (int t = 0; t < 4; ++t)
          vacc[t][n] = iv;
      }
      const unsigned short* wqp = qkv_wb + (size_t)((0 * 8 + w) * 2) * 4096 + lane * 8;
      const unsigned short* wkp = qkv_wb + (size_t)((1 * 8 + w) * 2) * 4096 + lane * 8;
      const unsigned short* wvp = qkv_wb + (size_t)((2 * 8 + w) * 2) * 4096 + lane * 8;
#pragma unroll
      for (int ks = 0; ks < 8; ++ks) {
        short8 xf[4];
#pragma unroll
        for (int t = 0; t < 4; ++t)
          xf[t] = *(const short8*)&xb[(t * 16 + lr) * 264 + ks * 32 + lg * 8];
        short8 wq[2], wk[2], wv[2];
#pragma unroll
        for (int m = 0; m < 2; ++m) {
          wq[m] = *(const short8*)&wqp[(m * 8 + ks) * 512];
          wk[m] = *(const short8*)&wkp[(m * 8 + ks) * 512];
          wv[m] = *(const short8*)&wvp[(m * 8 + ks) * 512];
        }
#pragma unroll
        for (int m = 0; m < 2; ++m)
#pragma unroll
          for (int t = 0; t < 4; ++t) {
            qacc[m][t] = MFMA32(wq[m], xf[t], qacc[m][t]);
            kacc[m][t] = MFMA32(wk[m], xf[t], kacc[m][t]);
            vacc[t][m] = MFMA32(xf[t], wv[m], vacc[t][m]);
          }
      }
#pragma unroll
      for (int m = 0; m < 2; ++m)
#pragma unroll
        for (int t = 0; t < 4; ++t)
#pragma unroll
          for (int e = 0; e < 4; ++e) {
            qh[m][t][e] = (_Float16)qacc[m][t][e];
            kh[m][t][e] = (_Float16)kacc[m][t][e];
            vh[t][m][e] = (_Float16)vacc[t][m][e];
          }
    }
    __syncthreads();   // B1: all waves done reading xb — xb (O-dest) free

    // issue window-1 x loads now (wi==0 only): latency hides under
    // softmax+PV; sched_barrier pins issue point (R12: compiler sinks).
    f32x4 rx1[8];
    if (wi == 0) {
      const f32x4* xg1 = (const f32x4*)(x + ((size_t)bid + 2048) * 16384);
#pragma unroll
      for (int i = 0; i < 8; ++i)
        rx1[i] = __builtin_nontemporal_load(&xg1[i * 512 + tid]);
      __builtin_amdgcn_sched_barrier(0);
    }

    // ---- Phase 3: S^T = k @ q^T (exp2-domain), C-init = rpe+mask;
    // pb = exp2(S) unnormalized; inv[it] applied after PV.
    half4 pb[4][4];    // [jt = PV k-step][it]
    float inv[4];
    {
      const float* rpe_h = rpe + (size_t)w * 4096 + lane * 4;   // packed
#pragma unroll
      for (int it = 0; it < 4; ++it) {
        f32x4 binit[4];
#pragma unroll
        for (int jt = 0; jt < 4; ++jt)
          binit[jt] = *(const f32x4*)&rpe_h[(it * 4 + jt) * 256];
#pragma unroll
        for (int jt = 0; jt < 4; ++jt) {
          f32x4 mv = *(const f32x4*)&mk[(it * 16 + lr) * 68 + jt * 16 + lg * 4];
#pragma unroll
          for (int e = 0; e < 4; ++e) binit[jt][e] += mv[e];
        }
        f32x4 sacc[4];
#pragma unroll
        for (int jt = 0; jt < 4; ++jt) {
          sacc[jt] = MFMA16(kh[0][jt], qh[0][it], binit[jt]);
          sacc[jt] = MFMA16(kh[1][jt], qh[1][it], sacc[jt]);
        }
        float sum = 0.f;
#pragma unroll
        for (int jt = 0; jt < 4; ++jt)
#pragma unroll
          for (int e = 0; e < 4; ++e) {
            sacc[jt][e] = exp2f(sacc[jt][e]);
            sum += sacc[jt][e];
          }
#pragma unroll
        for (int jt = 0; jt < 4; ++jt)
#pragma unroll
          for (int e = 0; e < 4; ++e)
            pb[jt][it][e] = (_Float16)sacc[jt][e];
        sum += __shfl_xor(sum, 16, 64);
        sum += __shfl_xor(sum, 32, 64);
        inv[it] = 1.0f / sum;
      }
    }

    // ---- Phase 4: O^T = V^T @ P^T (unnormalized); scale by inv[it]; -> xb
    {
      f32x4 oacc[2][4];   // [dt][it]
      const f32x4 z4 = {0.f, 0.f, 0.f, 0.f};
#pragma unroll
      for (int dt = 0; dt < 2; ++dt)
#pragma unroll
        for (int it = 0; it < 4; ++it)
          oacc[dt][it] = z4;
#pragma unroll
      for (int kj = 0; kj < 4; ++kj)
#pragma unroll
        for (int dt = 0; dt < 2; ++dt)
#pragma unroll
          for (int it = 0; it < 4; ++it)
            oacc[dt][it] = MFMA16(vh[kj][dt], pb[kj][it], oacc[dt][it]);
#pragma unroll
      for (int dt = 0; dt < 2; ++dt)
#pragma unroll
        for (int it = 0; it < 4; ++it)
          *(unsigned long long*)&xb[(it * 16 + lr) * 264 + w * 32 + dt * 16 + lg * 4]
              = pack4(oacc[dt][it][0] * inv[it], oacc[dt][it][1] * inv[it],
                      oacc[dt][it][2] * inv[it], oacc[dt][it][3] * inv[it]);
    }

    // pack window-1 x (loads long complete) into xb1; B2 publishes it
    if (wi == 0) {
#pragma unroll
      for (int i = 0; i < 8; ++i) {
        int vi = i * 512 + tid;
        *(unsigned long long*)&xb1[(vi >> 6) * 264 + (vi & 63) * 4]
            = pack4(rx1[i][0], rx1[i][1], rx1[i][2], rx1[i][3]);
      }
    }
    __syncthreads();   // B2: O_all (and xb1 on wi==0) visible

    // ---- Phase 5: out^T = proj_w @ O_all^T; bias in acc-init; nt stores
    {
      f32x4 pacc[2][4];
#pragma unroll
      for (int m = 0; m < 2; ++m) {
        f32x4 bp = *(const f32x4*)&proj_b[w * 32 + m * 16 + lg * 4];
#pragma unroll
        for (int t = 0; t < 4; ++t)
          pacc[m][t] = bp;
      }
      const unsigned short* pwp = proj_wb + (size_t)(w * 2) * 4096 + lane * 8;
#pragma unroll
      for (int ks = 0; ks < 8; ++ks) {
        short8 of[4];
#pragma unroll
        for (int t = 0; t < 4; ++t)
          of[t] = *(const short8*)&xb[(t * 16 + lr) * 264 + ks * 32 + lg * 8];
        short8 pw[2];
#pragma unroll
        for (int m = 0; m < 2; ++m)
          pw[m] = *(const short8*)&pwp[(m * 8 + ks) * 512];
#pragma unroll
        for (int m = 0; m < 2; ++m)
#pragma unroll
          for (int t = 0; t < 4; ++t)
            pacc[m][t] = MFMA32(pw[m], of[t], pacc[m][t]);
      }
      float* og = out + ((size_t)bid + (size_t)wi * 2048) * 16384;
#pragma unroll
      for (int m = 0; m < 2; ++m)
#pragma unroll
        for (int t = 0; t < 4; ++t)
          __builtin_nontemporal_store(pacc[m][t],
              (f32x4*)&og[(t * 16 + lr) * 256 + w * 32 + m * 16 + lg * 4]);
    }
  }
}

extern "C" void kernel_launch(void* const* d_in, const int* in_sizes, int n_in,
                              void* d_out, int out_size, void* d_ws, size_t ws_size,
                              hipStream_t stream) {
  (void)in_sizes; (void)n_in; (void)out_size; (void)ws_size;
  const float* x      = (const float*)d_in[0];
  const float* mask   = (const float*)d_in[1];
  const float* qkv_w  = (const float*)d_in[2];
  const float* qkv_b  = (const float*)d_in[3];
  const float* proj_w = (const float*)d_in[4];
  const float* proj_b = (const float*)d_in[5];
  const float* rpb    = (const float*)d_in[6];
  const int*   rel    = (const int*)d_in[7];

  unsigned short* qkv_wb  = (unsigned short*)d_ws;                       // 393216 B
  unsigned short* proj_wb = (unsigned short*)((char*)d_ws + 393216);     // 131072 B
  float*          rpe     = (float*)((char*)d_ws + 524288);              // 131072 B
  float*          qkv_bs  = (float*)((char*)d_ws + 655360);              // 3072 B
  float*          out     = (float*)d_out;

  prep_kernel<<<dim3(1155), dim3(256), 0, stream>>>(qkv_w, proj_w, rpb, rel, qkv_b,
                                                    qkv_wb, proj_wb, rpe, qkv_bs);
  win_attn_kernel<<<dim3(2048), dim3(512), 0, stream>>>(x, mask, qkv_wb, qkv_bs,
                                                        proj_wb, proj_b, rpe, out);
}